// Round 3
// baseline (1152.898 us; speedup 1.0000x reference)
//
#include <hip/hip_runtime.h>
#include <stdint.h>

// Problem constants
#define B_N 16384
#define DIMV 256
#define XSTRIDE 512            // floats per sample row (2 x 256)
#define EPSF 1e-6f
#define CEF 2.56e-10f          // d * EPS^2 = 256e-12
#define TWOEPS 2e-6f
#define MINING 0.1f
#define MARGINF 0.3f
#define NSTRIP 8

typedef __attribute__((ext_vector_type(8))) short bf16x8;
typedef __attribute__((ext_vector_type(4))) float f32x4;

// ---------------- JAX threefry2x32 (exact) ----------------
__device__ __forceinline__ void tf2x32(uint32_t k0, uint32_t k1,
                                       uint32_t& x0, uint32_t& x1) {
  uint32_t k2 = k0 ^ k1 ^ 0x1BD11BDAu;
  x0 += k0; x1 += k1;
#define TFR(r) { x0 += x1; x1 = (x1 << (r)) | (x1 >> (32 - (r))); x1 ^= x0; }
  TFR(13) TFR(15) TFR(26) TFR(6)
  x0 += k1; x1 += k2 + 1u;
  TFR(17) TFR(29) TFR(16) TFR(24)
  x0 += k2; x1 += k0 + 2u;
  TFR(13) TFR(15) TFR(26) TFR(6)
  x0 += k0; x1 += k1 + 3u;
  TFR(17) TFR(29) TFR(16) TFR(24)
  x0 += k1; x1 += k2 + 4u;
  TFR(13) TFR(15) TFR(26) TFR(6)
  x0 += k2; x1 += k0 + 5u;
#undef TFR
}

// rotate-left via single v_alignbit_b32 (alignbit(x,x,s) == rotr(x,s))
#define TF_ROT(x, r) __builtin_amdgcn_alignbit((x), (x), 32u - (r))

// Hot-path threefry: ctr=(0, c1), key=(K0,K1); returns 23-bit mantissa bits.
// All key-schedule constants are wave-uniform -> SGPRs, hoisted by LICM.
__device__ __forceinline__ uint32_t tf_mb(uint32_t K0, uint32_t K1, uint32_t c1) {
  const uint32_t K2 = K0 ^ K1 ^ 0x1BD11BDAu;
  uint32_t x0 = K0;            // c0 + k0 with c0 == 0
  uint32_t x1 = c1 + K1;
#define R4A { x0 += x1; x1 = TF_ROT(x1, 13); x1 ^= x0; \
              x0 += x1; x1 = TF_ROT(x1, 15); x1 ^= x0; \
              x0 += x1; x1 = TF_ROT(x1, 26); x1 ^= x0; \
              x0 += x1; x1 = TF_ROT(x1, 6);  x1 ^= x0; }
#define R4B { x0 += x1; x1 = TF_ROT(x1, 17); x1 ^= x0; \
              x0 += x1; x1 = TF_ROT(x1, 29); x1 ^= x0; \
              x0 += x1; x1 = TF_ROT(x1, 16); x1 ^= x0; \
              x0 += x1; x1 = TF_ROT(x1, 24); x1 ^= x0; }
  R4A; x0 += K1; x1 += K2 + 1u;
  R4B; x0 += K2; x1 += K0 + 2u;
  R4A; x0 += K0; x1 += K1 + 3u;
  R4B; x0 += K1; x1 += K2 + 4u;
  R4A; x0 += K2; x1 += K0 + 5u;
#undef R4A
#undef R4B
  return (x0 ^ x1) >> 9;
}

__device__ __forceinline__ float wave_sum(float v) {
#pragma unroll
  for (int off = 32; off > 0; off >>= 1) v += __shfl_xor(v, off, 64);
  return v;
}

// async global->LDS DMA, 16 B per lane; LDS dest = wave-uniform base + lane*16
__device__ __forceinline__ void gl_lds16(const unsigned short* g, unsigned short* s) {
  __builtin_amdgcn_global_load_lds(
      (const __attribute__((address_space(1))) void*)g,
      (__attribute__((address_space(3))) void*)s, 16, 0, 0);
}

// RNE fp32 -> bf16(hi) + bf16(v - hi), packed hi | lo<<16
__device__ __forceinline__ uint32_t split_pack(float v) {
  const uint32_t u = __float_as_uint(v);
  const uint32_t hi = (u + 0x7FFFu + ((u >> 16) & 1u)) >> 16;
  const float hf = __uint_as_float(hi << 16);
  const float lf = v - hf;
  const uint32_t ul = __float_as_uint(lf);
  const uint32_t lo = (ul + 0x7FFFu + ((ul >> 16) & 1u)) >> 16;
  return hi | (lo << 16);
}

// ---------------- K1: per-row stats (exact fp32) ----------------
__global__ void k1_stats(const float* __restrict__ x, float* __restrict__ invA,
                         float* __restrict__ invP, float* __restrict__ rowA,
                         float* __restrict__ colB, float* __restrict__ lo,
                         float* __restrict__ pos2) {
  const int i = blockIdx.x;
  const int l = threadIdx.x;  // 0..63
  const float4 va = *(const float4*)&x[i * XSTRIDE + l * 4];
  const float4 vp = *(const float4*)&x[i * XSTRIDE + DIMV + l * 4];
  float saa = va.x*va.x + va.y*va.y + va.z*va.z + va.w*va.w;
  float spp = vp.x*vp.x + vp.y*vp.y + vp.z*vp.z + vp.w*vp.w;
  saa = wave_sum(saa); spp = wave_sum(spp);
  const float ia = 1.0f / fmaxf(sqrtf(saa), 1e-12f);
  const float ip = 1.0f / fmaxf(sqrtf(spp), 1e-12f);
  const float ax = va.x*ia, ay = va.y*ia, az = va.z*ia, aw = va.w*ia;
  const float px = vp.x*ip, py = vp.y*ip, pz = vp.z*ip, pw = vp.w*ip;
  float na2 = ax*ax + ay*ay + az*az + aw*aw;
  float np2 = px*px + py*py + pz*pz + pw*pw;
  float sa  = ax + ay + az + aw;
  float sp  = px + py + pz + pw;
  float dii = ax*px + ay*py + az*pz + aw*pw;
  const float dx = ax-px+EPSF, dy = ay-py+EPSF, dz = az-pz+EPSF, dw = aw-pw+EPSF;
  float ps = dx*dx + dy*dy + dz*dz + dw*dw;
  na2 = wave_sum(na2); np2 = wave_sum(np2); sa = wave_sum(sa);
  sp  = wave_sum(sp);  dii = wave_sum(dii); ps = wave_sum(ps);
  if (l == 0) {
    const float rA = na2 + TWOEPS * sa + CEF;
    const float cB = np2 - TWOEPS * sp;
    invA[i] = ia; invP[i] = ip; rowA[i] = rA; colB[i] = cB;
    lo[i] = sqrtf(fmaxf(rA + cB - 2.0f * dii, 0.0f));
    pos2[i] = ps;
  }
}

// ---------------- K1b: fp32 -> interleaved bf16 hi/lo workspace ----------------
__global__ void k1b_cvt(const float* __restrict__ x, const float* __restrict__ invA,
                        const float* __restrict__ invP,
                        unsigned short* __restrict__ Abf,
                        unsigned short* __restrict__ Pbf) {
  const int t = blockIdx.x * 256 + threadIdx.x;
  const int row = t >> 6, l = t & 63;
  const float ia = invA[row], ip = invP[row];
  const float4 va = *(const float4*)&x[row * XSTRIDE + l * 4];
  const float4 vp = *(const float4*)&x[row * XSTRIDE + DIMV + l * 4];
  uint4 oa, op;
  oa.x = split_pack(va.x * ia); oa.y = split_pack(va.y * ia);
  oa.z = split_pack(va.z * ia); oa.w = split_pack(va.w * ia);
  op.x = split_pack(vp.x * ip); op.y = split_pack(vp.y * ip);
  op.z = split_pack(vp.z * ip); op.w = split_pack(vp.w * ip);
  *(uint4*)&Abf[(size_t)row * 512 + l * 8] = oa;
  *(uint4*)&Pbf[(size_t)row * 512 + l * 8] = op;
}

// ---------------- K2 (fast): MFMA distance GEMM + mask + threefry argmax ------
// grid (128 row-tiles, 8 strips), block 256 (4 waves, 2x2 of 64x64 wave tiles).
// launch_bounds(256,4): VGPR<=128, LDS 4x34KB<=160KB -> 4 blocks/CU so one
// block's threefry epilogue overlaps another's MFMA/staging phase.
__global__ __launch_bounds__(256, 4) void k2_mfma(
    const unsigned short* __restrict__ Abf, const unsigned short* __restrict__ Pbf,
    const float* __restrict__ rowA, const float* __restrict__ colB,
    const float* __restrict__ lo, unsigned long long* __restrict__ partials) {
  __shared__ __align__(16) unsigned short As[128 * 64];
  __shared__ __align__(16) unsigned short Bs[128 * 64];
  __shared__ unsigned long long red[128][2];

  const int tid = threadIdx.x;
  const int w = tid >> 6;
  const int l = tid & 63;
  const int q = l >> 4;
  const int c16 = l & 15;
  const int rBase = blockIdx.x * 128;
  const int strip = blockIdx.y;
  const int wR = (w >> 1) * 64;
  const int wC = (w & 1) * 64;

  // threefry subkey k1 = block(ctr=(0,0), key=(0,1)) -- wave-uniform (SGPR)
  uint32_t K0 = 0u, K1 = 0u;
  tf2x32(0u, 1u, K0, K1);

  const int sw = c16 & 7;                    // frag-read xor (row&7 == c16&7)
  const int sgk = (l & 7) ^ ((l >> 3) & 7);  // staging lane's global k-group

  const int arow = rBase + w * 32 + (l >> 3);
  const unsigned short* gA0 = Abf + (size_t)arow * 512 + sgk * 8;
  unsigned short* lA0 = &As[(w * 32) * 64];
  unsigned short* lB0 = &Bs[(w * 32) * 64];

  // per-row mask bounds in D^2-space, with rowA folded in:
  //  mask <=> Lr < colB - 2*dot < Hr
  float Lr[16], Hr[16];
  const int iBase = rBase + wR + q * 4;
#pragma unroll
  for (int ri = 0; ri < 16; ++ri) {
    const int i = iBase + (ri >> 2) * 16 + (ri & 3);
    const float ra = rowA[i];
    const float lv = lo[i];
    Lr[ri] = lv * lv - ra;
    Hr[ri] = (lv + MINING) * (lv + MINING) - ra;
  }

  // 32-bit running argmax state. Per-thread scan order is strictly
  // increasing j, so strict-greater keeps the smallest j on mb ties --
  // exactly JAX argmax first-index semantics.
  int bmb[16], bj[16];
#pragma unroll
  for (int ri = 0; ri < 16; ++ri) { bmb[ri] = -1; bj[ri] = 0; }

  for (int ct = 0; ct < 16; ++ct) {
    const int cBase = strip * 2048 + ct * 128;
    const int brow = cBase + w * 32 + (l >> 3);
    const unsigned short* gB0 = Pbf + (size_t)brow * 512 + sgk * 8;

    f32x4 acc[4][4];
#pragma unroll
    for (int m = 0; m < 4; ++m)
#pragma unroll
      for (int n = 0; n < 4; ++n) {
        f32x4 z = {0.0f, 0.0f, 0.0f, 0.0f};
        acc[m][n] = z;
      }

    for (int kc = 0; kc < 512; kc += 64) {
      __syncthreads();
#pragma unroll
      for (int u = 0; u < 4; ++u) {
        gl_lds16(gA0 + kc + u * 8 * 512, lA0 + u * 8 * 64);
        gl_lds16(gB0 + kc + u * 8 * 512, lB0 + u * 8 * 64);
      }
      __syncthreads();
#pragma unroll
      for (int ks = 0; ks < 2; ++ks) {
        const int px = ((ks * 4 + q) ^ sw) * 8;
        bf16x8 am[4], bn[4];
#pragma unroll
        for (int m = 0; m < 4; ++m)
          am[m] = *(const bf16x8*)&As[(wR + m * 16 + c16) * 64 + px];
#pragma unroll
        for (int n = 0; n < 4; ++n)
          bn[n] = *(const bf16x8*)&Bs[(wC + n * 16 + c16) * 64 + px];
#pragma unroll
        for (int m = 0; m < 4; ++m)
#pragma unroll
          for (int n = 0; n < 4; ++n)
            acc[m][n] = __builtin_amdgcn_mfma_f32_16x16x32_bf16(
                am[m], bn[n], acc[m][n], 0, 0, 0);
      }
    }

    // epilogue: mask + threefry + running argmax (unconditional threefry --
    // ~45% mask density makes wave-granularity skipping worthless)
    int jc[4]; float colBc[4];
#pragma unroll
    for (int n = 0; n < 4; ++n) {
      jc[n] = cBase + wC + n * 16 + c16;
      colBc[n] = colB[jc[n]];
    }
#pragma unroll
    for (int ri = 0; ri < 16; ++ri) {
      const int m = ri >> 2, r = ri & 3;
      const int i = iBase + m * 16 + r;
      const uint32_t ihi = ((uint32_t)i) << 14;
      const float Lv = Lr[ri], Hv = Hr[ri];
      int b = bmb[ri], j0 = bj[ri];
#pragma unroll
      for (int n = 0; n < 4; ++n) {
        const float t = fmaf(-2.0f, acc[m][n][r], colBc[n]);
        const uint32_t mb = tf_mb(K0, K1, ihi | (uint32_t)jc[n]);
        const bool upd = (t > Lv) & (t < Hv) & (jc[n] != i) & ((int)mb > b);
        b  = upd ? (int)mb : b;
        j0 = upd ? jc[n] : j0;
      }
      bmb[ri] = b; bj[ri] = j0;
    }
  }

  // pack (mb, j) -> 64-bit key, reduce across the 16 col-lanes, then across
  // the 2 col-wave-groups
#pragma unroll
  for (int ri = 0; ri < 16; ++ri) {
    unsigned long long bk = 0ull;
    if (bmb[ri] >= 0)
      bk = ((unsigned long long)(uint32_t)(bmb[ri] + 1) << 32) |
           (unsigned long long)(uint32_t)(16383 - bj[ri]);
#pragma unroll
    for (int off = 1; off < 16; off <<= 1) {
      const unsigned long long o = __shfl_xor(bk, off, 64);
      if (o > bk) bk = o;
    }
    if (c16 == 0) red[wR + (ri >> 2) * 16 + q * 4 + (ri & 3)][w & 1] = bk;
  }
  __syncthreads();
  if (tid < 128) {
    const unsigned long long g0 = red[tid][0], g1 = red[tid][1];
    partials[(size_t)(rBase + tid) * NSTRIP + strip] = g0 > g1 ? g0 : g1;
  }
}

// ---------------- K2 (fallback, fp32 vector version) ----------------
#define TM 64
#define TN 128
#define KC 64
#define AS_LD 68
#define BS_LD 132
#define COLS_PER_STRIP (B_N / NSTRIP)
#define TILES_PER_STRIP (COLS_PER_STRIP / TN)

__global__ __launch_bounds__(256, 3) void k2_mine(
    const float* __restrict__ x, const float* __restrict__ invA,
    const float* __restrict__ invP, const float* __restrict__ rowA,
    const float* __restrict__ colB, const float* __restrict__ lo,
    unsigned long long* __restrict__ partials) {
  __shared__ __align__(16) float As[KC * AS_LD];
  __shared__ __align__(16) float Bs[KC * BS_LD];
  __shared__ float colBs[TN];

  const int tid = threadIdx.x;
  const int ty = tid >> 4;
  const int tx = tid & 15;
  const int rBase = blockIdx.x * TM;
  const int strip = blockIdx.y;
  const int cStart = strip * COLS_PER_STRIP;

  uint32_t k1h = 0u, k1l = 0u;
  tf2x32(0u, 1u, k1h, k1l);

  float rowA_r[4], lo_r[4];
  int rows[4];
#pragma unroll
  for (int m = 0; m < 4; ++m) {
    rows[m] = rBase + ty * 4 + m;
    rowA_r[m] = rowA[rows[m]];
    lo_r[m] = lo[rows[m]];
  }

  unsigned long long best[4] = {0ull, 0ull, 0ull, 0ull};
  const int skq = tid & 15;
  const int srr = tid >> 4;

  for (int ct = 0; ct < TILES_PER_STRIP; ++ct) {
    const int cBase = cStart + ct * TN;
    float acc[4][8];
#pragma unroll
    for (int m = 0; m < 4; ++m)
#pragma unroll
      for (int n = 0; n < 8; ++n) acc[m][n] = 0.0f;

    for (int kc = 0; kc < DIMV; kc += KC) {
      __syncthreads();
#pragma unroll
      for (int u = 0; u < 4; ++u) {
        const int r = srr + 16 * u;
        const int row = rBase + r;
        const float4 v = *(const float4*)&x[row * XSTRIDE + kc + skq * 4];
        const float s = invA[row];
        As[(skq * 4 + 0) * AS_LD + r] = v.x * s;
        As[(skq * 4 + 1) * AS_LD + r] = v.y * s;
        As[(skq * 4 + 2) * AS_LD + r] = v.z * s;
        As[(skq * 4 + 3) * AS_LD + r] = v.w * s;
      }
#pragma unroll
      for (int u = 0; u < 8; ++u) {
        const int c = srr + 16 * u;
        const int col = cBase + c;
        const float4 v = *(const float4*)&x[col * XSTRIDE + DIMV + kc + skq * 4];
        const float s = invP[col];
        Bs[(skq * 4 + 0) * BS_LD + c] = v.x * s;
        Bs[(skq * 4 + 1) * BS_LD + c] = v.y * s;
        Bs[(skq * 4 + 2) * BS_LD + c] = v.z * s;
        Bs[(skq * 4 + 3) * BS_LD + c] = v.w * s;
      }
      if (kc == 0 && tid < TN) colBs[tid] = colB[cBase + tid];
      __syncthreads();

#pragma unroll 8
      for (int k = 0; k < KC; ++k) {
        const float4 a4 = *(const float4*)&As[k * AS_LD + ty * 4];
        const float4 bl = *(const float4*)&Bs[k * BS_LD + tx * 4];
        const float4 bh = *(const float4*)&Bs[k * BS_LD + 64 + tx * 4];
        const float am[4] = {a4.x, a4.y, a4.z, a4.w};
        const float bn[8] = {bl.x, bl.y, bl.z, bl.w, bh.x, bh.y, bh.z, bh.w};
#pragma unroll
        for (int m = 0; m < 4; ++m)
#pragma unroll
          for (int n = 0; n < 8; ++n)
            acc[m][n] = fmaf(am[m], bn[n], acc[m][n]);
      }
    }

#pragma unroll
    for (int m = 0; m < 4; ++m) {
      const int i = rows[m];
      const float loi = lo_r[m];
      const float hii = loi + MINING;
#pragma unroll
      for (int n = 0; n < 8; ++n) {
        const int cOff = (n < 4) ? (tx * 4 + n) : (64 + tx * 4 + (n - 4));
        const int j = cBase + cOff;
        const float D2 = rowA_r[m] + colBs[cOff] - 2.0f * acc[m][n];
        const float D = sqrtf(fmaxf(D2, 0.0f));
        if (D > loi && D < hii && j != i) {
          uint32_t c0 = 0u;
          uint32_t c1 = ((uint32_t)i << 14) | (uint32_t)j;
          tf2x32(k1h, k1l, c0, c1);
          const uint32_t bits = c0 ^ c1;
          const uint32_t mb = bits >> 9;
          const unsigned long long pk =
              ((unsigned long long)(mb + 1u) << 32) |
              (unsigned long long)(uint32_t)(16383 - j);
          if (pk > best[m]) best[m] = pk;
        }
      }
    }
  }

  __syncthreads();
  unsigned long long* red = (unsigned long long*)As;
#pragma unroll
  for (int m = 0; m < 4; ++m) red[(ty * 4 + m) * 16 + tx] = best[m];
  __syncthreads();
  if (tid < TM) {
    unsigned long long g = red[tid * 16];
#pragma unroll
    for (int t = 1; t < 16; ++t) {
      const unsigned long long v = red[tid * 16 + t];
      if (v > g) g = v;
    }
    partials[(size_t)(rBase + tid) * NSTRIP + strip] = g;
  }
}

// ---------------- K3: combine strips + fallback randint ----------------
__global__ void k3_select(const unsigned long long* __restrict__ partials,
                          int* __restrict__ negidx) {
  const int i = blockIdx.x * 256 + threadIdx.x;
  unsigned long long g = 0ull;
#pragma unroll
  for (int s = 0; s < NSTRIP; ++s) {
    const unsigned long long v = partials[(size_t)i * NSTRIP + s];
    if (v > g) g = v;
  }
  int ng;
  if (g != 0ull) {
    ng = 16383 - (int)(g & 0xFFFFFFFFull);
  } else {
    uint32_t t0 = 0u, t1 = 1u;            // k2 = block(ctr=(0,1), root)
    tf2x32(0u, 1u, t0, t1);
    uint32_t u0 = 0u, u1 = 1u;            // k2b = block(ctr=(0,1), k2)
    tf2x32(t0, t1, u0, u1);
    uint32_t v0 = 0u, v1 = (uint32_t)i;   // lower_bits[i]
    tf2x32(u0, u1, v0, v1);
    ng = (int)((v0 ^ v1) & 16383u);
  }
  negidx[i] = ng;
}

// ---------------- K4: gather negatives + per-row loss ----------------
__global__ void k4_loss(const float* __restrict__ x, const float* __restrict__ invA,
                        const float* __restrict__ invP, const float* __restrict__ pos2,
                        const int* __restrict__ negidx, float* __restrict__ bsums) {
  const int w = threadIdx.x >> 6;
  const int l = threadIdx.x & 63;
  const int i = blockIdx.x * 4 + w;
  const float ia = invA[i];
  const int ng = negidx[i];
  const float ip = invP[ng];
  const float4 va = *(const float4*)&x[i * XSTRIDE + l * 4];
  const float4 vn = *(const float4*)&x[ng * XSTRIDE + DIMV + l * 4];
  const float dx = va.x * ia - vn.x * ip + EPSF;
  const float dy = va.y * ia - vn.y * ip + EPSF;
  const float dz = va.z * ia - vn.z * ip + EPSF;
  const float dw = va.w * ia - vn.w * ip + EPSF;
  float s = dx*dx + dy*dy + dz*dz + dw*dw;
  s = wave_sum(s);
  __shared__ float bs[4];
  if (l == 0) bs[w] = fmaxf(pos2[i] - s + MARGINF, 0.0f);
  __syncthreads();
  if (threadIdx.x == 0) bsums[blockIdx.x] = bs[0] + bs[1] + bs[2] + bs[3];
}

// ---------------- K5: final reduce ----------------
__global__ void k5_reduce(const float* __restrict__ bsums, float* __restrict__ out) {
  float s = 0.0f;
  for (int idx = threadIdx.x; idx < (B_N / 4); idx += 256) s += bsums[idx];
  s = wave_sum(s);
  __shared__ float acc4[4];
  if ((threadIdx.x & 63) == 0) acc4[threadIdx.x >> 6] = s;
  __syncthreads();
  if (threadIdx.x == 0)
    out[0] = (acc4[0] + acc4[1] + acc4[2] + acc4[3]) * (1.0f / (float)B_N);
}

extern "C" void kernel_launch(void* const* d_in, const int* in_sizes, int n_in,
                              void* d_out, int out_size, void* d_ws, size_t ws_size,
                              hipStream_t stream) {
  const float* x = (const float*)d_in[0];
  char* ws = (char*)d_ws;
  size_t off = 0;
  unsigned long long* partials = (unsigned long long*)(ws + off);
  off += (size_t)B_N * NSTRIP * sizeof(unsigned long long);   // 1 MiB
  float* invA = (float*)(ws + off); off += (size_t)B_N * 4;
  float* invP = (float*)(ws + off); off += (size_t)B_N * 4;
  float* rowA = (float*)(ws + off); off += (size_t)B_N * 4;
  float* colB = (float*)(ws + off); off += (size_t)B_N * 4;
  float* lo   = (float*)(ws + off); off += (size_t)B_N * 4;
  float* pos2 = (float*)(ws + off); off += (size_t)B_N * 4;
  int* negidx = (int*)(ws + off);   off += (size_t)B_N * 4;
  float* bsums = (float*)(ws + off); off += (size_t)(B_N / 4) * 4;
  unsigned short* Abf = (unsigned short*)(ws + off);
  off += (size_t)B_N * 512 * sizeof(unsigned short);          // 16 MiB
  unsigned short* Pbf = (unsigned short*)(ws + off);
  off += (size_t)B_N * 512 * sizeof(unsigned short);          // 16 MiB
  const size_t ws_need = off;
  float* out = (float*)d_out;

  hipLaunchKernelGGL(k1_stats, dim3(B_N), dim3(64), 0, stream,
                     x, invA, invP, rowA, colB, lo, pos2);
  if (ws_size >= ws_need) {
    hipLaunchKernelGGL(k1b_cvt, dim3(B_N / 4), dim3(256), 0, stream,
                       x, invA, invP, Abf, Pbf);
    hipLaunchKernelGGL(k2_mfma, dim3(B_N / 128, NSTRIP), dim3(256), 0, stream,
                       Abf, Pbf, rowA, colB, lo, partials);
  } else {
    hipLaunchKernelGGL(k2_mine, dim3(B_N / TM, NSTRIP), dim3(256), 0, stream,
                       x, invA, invP, rowA, colB, lo, partials);
  }
  hipLaunchKernelGGL(k3_select, dim3(B_N / 256), dim3(256), 0, stream,
                     partials, negidx);
  hipLaunchKernelGGL(k4_loss, dim3(B_N / 4), dim3(256), 0, stream,
                     x, invA, invP, pos2, negidx, bsums);
  hipLaunchKernelGGL(k5_reduce, dim3(1), dim3(256), 0, stream, bsums, out);
}

// Round 4
// 1054.026 us; speedup vs baseline: 1.0938x; 1.0938x over previous
//
#include <hip/hip_runtime.h>
#include <stdint.h>

// Problem constants
#define B_N 16384
#define DIMV 256
#define XSTRIDE 512            // floats per sample row (2 x 256)
#define EPSF 1e-6f
#define CEF 2.56e-10f          // d * EPS^2 = 256e-12
#define TWOEPS 2e-6f
#define MINING 0.1f
#define MARGINF 0.3f
#define NSTRIP 8

typedef __attribute__((ext_vector_type(8))) short bf16x8;
typedef __attribute__((ext_vector_type(4))) float f32x4;

// ---------------- JAX threefry2x32 (exact) ----------------
__device__ __forceinline__ void tf2x32(uint32_t k0, uint32_t k1,
                                       uint32_t& x0, uint32_t& x1) {
  uint32_t k2 = k0 ^ k1 ^ 0x1BD11BDAu;
  x0 += k0; x1 += k1;
#define TFR(r) { x0 += x1; x1 = (x1 << (r)) | (x1 >> (32 - (r))); x1 ^= x0; }
  TFR(13) TFR(15) TFR(26) TFR(6)
  x0 += k1; x1 += k2 + 1u;
  TFR(17) TFR(29) TFR(16) TFR(24)
  x0 += k2; x1 += k0 + 2u;
  TFR(13) TFR(15) TFR(26) TFR(6)
  x0 += k0; x1 += k1 + 3u;
  TFR(17) TFR(29) TFR(16) TFR(24)
  x0 += k1; x1 += k2 + 4u;
  TFR(13) TFR(15) TFR(26) TFR(6)
  x0 += k2; x1 += k0 + 5u;
#undef TFR
}

// rotate via single v_alignbit_b32 (alignbit(x,x,s) == rotr(x,s))
#define TF_ROT(x, r) __builtin_amdgcn_alignbit((x), (x), 32u - (r))

// Hot-path threefry: ctr=(0, c1), key=(K0,K1); returns 23-bit mantissa bits.
// Key-schedule constants are wave-uniform -> SGPRs, hoisted by LICM.
__device__ __forceinline__ uint32_t tf_mb(uint32_t K0, uint32_t K1, uint32_t c1) {
  const uint32_t K2 = K0 ^ K1 ^ 0x1BD11BDAu;
  uint32_t x0 = K0;            // c0 + k0 with c0 == 0
  uint32_t x1 = c1 + K1;
#define R4A { x0 += x1; x1 = TF_ROT(x1, 13); x1 ^= x0; \
              x0 += x1; x1 = TF_ROT(x1, 15); x1 ^= x0; \
              x0 += x1; x1 = TF_ROT(x1, 26); x1 ^= x0; \
              x0 += x1; x1 = TF_ROT(x1, 6);  x1 ^= x0; }
#define R4B { x0 += x1; x1 = TF_ROT(x1, 17); x1 ^= x0; \
              x0 += x1; x1 = TF_ROT(x1, 29); x1 ^= x0; \
              x0 += x1; x1 = TF_ROT(x1, 16); x1 ^= x0; \
              x0 += x1; x1 = TF_ROT(x1, 24); x1 ^= x0; }
  R4A; x0 += K1; x1 += K2 + 1u;
  R4B; x0 += K2; x1 += K0 + 2u;
  R4A; x0 += K0; x1 += K1 + 3u;
  R4B; x0 += K1; x1 += K2 + 4u;
  R4A; x0 += K2; x1 += K0 + 5u;
#undef R4A
#undef R4B
  return (x0 ^ x1) >> 9;
}

__device__ __forceinline__ float wave_sum(float v) {
#pragma unroll
  for (int off = 32; off > 0; off >>= 1) v += __shfl_xor(v, off, 64);
  return v;
}

// async global->LDS DMA, 16 B per lane; LDS dest = wave-uniform base + lane*16
__device__ __forceinline__ void gl_lds16(const unsigned short* g, unsigned short* s) {
  __builtin_amdgcn_global_load_lds(
      (const __attribute__((address_space(1))) void*)g,
      (__attribute__((address_space(3))) void*)s, 16, 0, 0);
}

// RNE fp32 -> bf16(hi) + bf16(v - hi), packed hi | lo<<16
__device__ __forceinline__ uint32_t split_pack(float v) {
  const uint32_t u = __float_as_uint(v);
  const uint32_t hi = (u + 0x7FFFu + ((u >> 16) & 1u)) >> 16;
  const float hf = __uint_as_float(hi << 16);
  const float lf = v - hf;
  const uint32_t ul = __float_as_uint(lf);
  const uint32_t lo = (ul + 0x7FFFu + ((ul >> 16) & 1u)) >> 16;
  return hi | (lo << 16);
}

// ---------------- K1: per-row stats (exact fp32) ----------------
__global__ void k1_stats(const float* __restrict__ x, float* __restrict__ invA,
                         float* __restrict__ invP, float* __restrict__ rowA,
                         float* __restrict__ colB, float* __restrict__ lo,
                         float* __restrict__ pos2) {
  const int i = blockIdx.x;
  const int l = threadIdx.x;  // 0..63
  const float4 va = *(const float4*)&x[i * XSTRIDE + l * 4];
  const float4 vp = *(const float4*)&x[i * XSTRIDE + DIMV + l * 4];
  float saa = va.x*va.x + va.y*va.y + va.z*va.z + va.w*va.w;
  float spp = vp.x*vp.x + vp.y*vp.y + vp.z*vp.z + vp.w*vp.w;
  saa = wave_sum(saa); spp = wave_sum(spp);
  const float ia = 1.0f / fmaxf(sqrtf(saa), 1e-12f);
  const float ip = 1.0f / fmaxf(sqrtf(spp), 1e-12f);
  const float ax = va.x*ia, ay = va.y*ia, az = va.z*ia, aw = va.w*ia;
  const float px = vp.x*ip, py = vp.y*ip, pz = vp.z*ip, pw = vp.w*ip;
  float na2 = ax*ax + ay*ay + az*az + aw*aw;
  float np2 = px*px + py*py + pz*pz + pw*pw;
  float sa  = ax + ay + az + aw;
  float sp  = px + py + pz + pw;
  float dii = ax*px + ay*py + az*pz + aw*pw;
  const float dx = ax-px+EPSF, dy = ay-py+EPSF, dz = az-pz+EPSF, dw = aw-pw+EPSF;
  float ps = dx*dx + dy*dy + dz*dz + dw*dw;
  na2 = wave_sum(na2); np2 = wave_sum(np2); sa = wave_sum(sa);
  sp  = wave_sum(sp);  dii = wave_sum(dii); ps = wave_sum(ps);
  if (l == 0) {
    const float rA = na2 + TWOEPS * sa + CEF;
    const float cB = np2 - TWOEPS * sp;
    invA[i] = ia; invP[i] = ip; rowA[i] = rA; colB[i] = cB;
    lo[i] = sqrtf(fmaxf(rA + cB - 2.0f * dii, 0.0f));
    pos2[i] = ps;
  }
}

// ---------------- K1b: fp32 -> interleaved bf16 hi/lo workspace ----------------
__global__ void k1b_cvt(const float* __restrict__ x, const float* __restrict__ invA,
                        const float* __restrict__ invP,
                        unsigned short* __restrict__ Abf,
                        unsigned short* __restrict__ Pbf) {
  const int t = blockIdx.x * 256 + threadIdx.x;
  const int row = t >> 6, l = t & 63;
  const float ia = invA[row], ip = invP[row];
  const float4 va = *(const float4*)&x[row * XSTRIDE + l * 4];
  const float4 vp = *(const float4*)&x[row * XSTRIDE + DIMV + l * 4];
  uint4 oa, op;
  oa.x = split_pack(va.x * ia); oa.y = split_pack(va.y * ia);
  oa.z = split_pack(va.z * ia); oa.w = split_pack(va.w * ia);
  op.x = split_pack(vp.x * ip); op.y = split_pack(vp.y * ip);
  op.z = split_pack(vp.z * ip); op.w = split_pack(vp.w * ip);
  *(uint4*)&Abf[(size_t)row * 512 + l * 8] = oa;
  *(uint4*)&Pbf[(size_t)row * 512 + l * 8] = op;
}

// ---------------- K2 (fast): MFMA distance GEMM + mask + threefry argmax ------
// grid (128 row-tiles, 8 strips), block 256 (4 waves, 2x2 of 64x64 wave tiles).
// launch_bounds(256,3): VGPR cap 170 -- R3's (256,4) cap of 128 forced the
// ~160-reg live state into scratch (WRITE_SIZE 2MB -> 820MB, 830 -> 1153us).
__global__ __launch_bounds__(256, 3) void k2_mfma(
    const unsigned short* __restrict__ Abf, const unsigned short* __restrict__ Pbf,
    const float* __restrict__ rowA, const float* __restrict__ colB,
    const float* __restrict__ lo, unsigned long long* __restrict__ partials) {
  __shared__ __align__(16) unsigned short As[128 * 64];
  __shared__ __align__(16) unsigned short Bs[128 * 64];
  __shared__ unsigned long long red[128][2];

  const int tid = threadIdx.x;
  const int w = tid >> 6;
  const int l = tid & 63;
  const int q = l >> 4;
  const int c16 = l & 15;
  const int rBase = blockIdx.x * 128;
  const int strip = blockIdx.y;
  const int wR = (w >> 1) * 64;
  const int wC = (w & 1) * 64;

  // threefry subkey k1 = block(ctr=(0,0), key=(0,1)) -- wave-uniform (SGPR)
  uint32_t K0 = 0u, K1 = 0u;
  tf2x32(0u, 1u, K0, K1);

  const int sw = c16 & 7;                    // frag-read xor (row&7 == c16&7)
  const int sgk = (l & 7) ^ ((l >> 3) & 7);  // staging lane's global k-group

  const int arow = rBase + w * 32 + (l >> 3);
  const unsigned short* gA0 = Abf + (size_t)arow * 512 + sgk * 8;
  unsigned short* lA0 = &As[(w * 32) * 64];
  unsigned short* lB0 = &Bs[(w * 32) * 64];

  // per-row mask bounds in D^2-space, with rowA folded in:
  //  mask <=> Lr < colB - 2*dot < Hr
  float Lr[16], Hr[16];
  const int iBase = rBase + wR + q * 4;
#pragma unroll
  for (int ri = 0; ri < 16; ++ri) {
    const int i = iBase + (ri >> 2) * 16 + (ri & 3);
    const float ra = rowA[i];
    const float lv = lo[i];
    Lr[ri] = lv * lv - ra;
    Hr[ri] = (lv + MINING) * (lv + MINING) - ra;
  }

  // 32-bit running argmax state. Per-thread scan order is strictly
  // increasing j, so strict-greater keeps the smallest j on mb ties --
  // exactly JAX argmax first-index semantics.
  int bmb[16], bj[16];
#pragma unroll
  for (int ri = 0; ri < 16; ++ri) { bmb[ri] = -1; bj[ri] = 0; }

  for (int ct = 0; ct < 16; ++ct) {
    const int cBase = strip * 2048 + ct * 128;
    const int brow = cBase + w * 32 + (l >> 3);
    const unsigned short* gB0 = Pbf + (size_t)brow * 512 + sgk * 8;

    f32x4 acc[4][4];
#pragma unroll
    for (int m = 0; m < 4; ++m)
#pragma unroll
      for (int n = 0; n < 4; ++n) {
        f32x4 z = {0.0f, 0.0f, 0.0f, 0.0f};
        acc[m][n] = z;
      }

    for (int kc = 0; kc < 512; kc += 64) {
      __syncthreads();
#pragma unroll
      for (int u = 0; u < 4; ++u) {
        gl_lds16(gA0 + kc + u * 8 * 512, lA0 + u * 8 * 64);
        gl_lds16(gB0 + kc + u * 8 * 512, lB0 + u * 8 * 64);
      }
      __syncthreads();
#pragma unroll
      for (int ks = 0; ks < 2; ++ks) {
        const int px = ((ks * 4 + q) ^ sw) * 8;
        bf16x8 am[4], bn[4];
#pragma unroll
        for (int m = 0; m < 4; ++m)
          am[m] = *(const bf16x8*)&As[(wR + m * 16 + c16) * 64 + px];
#pragma unroll
        for (int n = 0; n < 4; ++n)
          bn[n] = *(const bf16x8*)&Bs[(wC + n * 16 + c16) * 64 + px];
#pragma unroll
        for (int m = 0; m < 4; ++m)
#pragma unroll
          for (int n = 0; n < 4; ++n)
            acc[m][n] = __builtin_amdgcn_mfma_f32_16x16x32_bf16(
                am[m], bn[n], acc[m][n], 0, 0, 0);
      }
    }

    // epilogue: mask + threefry + running argmax (unconditional threefry --
    // ~45% mask density makes wave-granularity skipping worthless)
    int jc[4]; float colBc[4];
#pragma unroll
    for (int n = 0; n < 4; ++n) {
      jc[n] = cBase + wC + n * 16 + c16;
      colBc[n] = colB[jc[n]];
    }
#pragma unroll
    for (int ri = 0; ri < 16; ++ri) {
      const int m = ri >> 2, r = ri & 3;
      const int i = iBase + m * 16 + r;
      const uint32_t ihi = ((uint32_t)i) << 14;
      const float Lv = Lr[ri], Hv = Hr[ri];
      int b = bmb[ri], j0 = bj[ri];
#pragma unroll
      for (int n = 0; n < 4; ++n) {
        const float t = fmaf(-2.0f, acc[m][n][r], colBc[n]);
        const uint32_t mb = tf_mb(K0, K1, ihi | (uint32_t)jc[n]);
        const bool upd = (t > Lv) & (t < Hv) & (jc[n] != i) & ((int)mb > b);
        b  = upd ? (int)mb : b;
        j0 = upd ? jc[n] : j0;
      }
      bmb[ri] = b; bj[ri] = j0;
    }
  }

  // pack (mb, j) -> 64-bit key, reduce across the 16 col-lanes, then across
  // the 2 col-wave-groups
#pragma unroll
  for (int ri = 0; ri < 16; ++ri) {
    unsigned long long bk = 0ull;
    if (bmb[ri] >= 0)
      bk = ((unsigned long long)(uint32_t)(bmb[ri] + 1) << 32) |
           (unsigned long long)(uint32_t)(16383 - bj[ri]);
#pragma unroll
    for (int off = 1; off < 16; off <<= 1) {
      const unsigned long long o = __shfl_xor(bk, off, 64);
      if (o > bk) bk = o;
    }
    if (c16 == 0) red[wR + (ri >> 2) * 16 + q * 4 + (ri & 3)][w & 1] = bk;
  }
  __syncthreads();
  if (tid < 128) {
    const unsigned long long g0 = red[tid][0], g1 = red[tid][1];
    partials[(size_t)(rBase + tid) * NSTRIP + strip] = g0 > g1 ? g0 : g1;
  }
}

// ---------------- K2 (fallback, fp32 vector version) ----------------
#define TM 64
#define TN 128
#define KC 64
#define AS_LD 68
#define BS_LD 132
#define COLS_PER_STRIP (B_N / NSTRIP)
#define TILES_PER_STRIP (COLS_PER_STRIP / TN)

__global__ __launch_bounds__(256, 3) void k2_mine(
    const float* __restrict__ x, const float* __restrict__ invA,
    const float* __restrict__ invP, const float* __restrict__ rowA,
    const float* __restrict__ colB, const float* __restrict__ lo,
    unsigned long long* __restrict__ partials) {
  __shared__ __align__(16) float As[KC * AS_LD];
  __shared__ __align__(16) float Bs[KC * BS_LD];
  __shared__ float colBs[TN];

  const int tid = threadIdx.x;
  const int ty = tid >> 4;
  const int tx = tid & 15;
  const int rBase = blockIdx.x * TM;
  const int strip = blockIdx.y;
  const int cStart = strip * COLS_PER_STRIP;

  uint32_t k1h = 0u, k1l = 0u;
  tf2x32(0u, 1u, k1h, k1l);

  float rowA_r[4], lo_r[4];
  int rows[4];
#pragma unroll
  for (int m = 0; m < 4; ++m) {
    rows[m] = rBase + ty * 4 + m;
    rowA_r[m] = rowA[rows[m]];
    lo_r[m] = lo[rows[m]];
  }

  unsigned long long best[4] = {0ull, 0ull, 0ull, 0ull};
  const int skq = tid & 15;
  const int srr = tid >> 4;

  for (int ct = 0; ct < TILES_PER_STRIP; ++ct) {
    const int cBase = cStart + ct * TN;
    float acc[4][8];
#pragma unroll
    for (int m = 0; m < 4; ++m)
#pragma unroll
      for (int n = 0; n < 8; ++n) acc[m][n] = 0.0f;

    for (int kc = 0; kc < DIMV; kc += KC) {
      __syncthreads();
#pragma unroll
      for (int u = 0; u < 4; ++u) {
        const int r = srr + 16 * u;
        const int row = rBase + r;
        const float4 v = *(const float4*)&x[row * XSTRIDE + kc + skq * 4];
        const float s = invA[row];
        As[(skq * 4 + 0) * AS_LD + r] = v.x * s;
        As[(skq * 4 + 1) * AS_LD + r] = v.y * s;
        As[(skq * 4 + 2) * AS_LD + r] = v.z * s;
        As[(skq * 4 + 3) * AS_LD + r] = v.w * s;
      }
#pragma unroll
      for (int u = 0; u < 8; ++u) {
        const int c = srr + 16 * u;
        const int col = cBase + c;
        const float4 v = *(const float4*)&x[col * XSTRIDE + DIMV + kc + skq * 4];
        const float s = invP[col];
        Bs[(skq * 4 + 0) * BS_LD + c] = v.x * s;
        Bs[(skq * 4 + 1) * BS_LD + c] = v.y * s;
        Bs[(skq * 4 + 2) * BS_LD + c] = v.z * s;
        Bs[(skq * 4 + 3) * BS_LD + c] = v.w * s;
      }
      if (kc == 0 && tid < TN) colBs[tid] = colB[cBase + tid];
      __syncthreads();

#pragma unroll 8
      for (int k = 0; k < KC; ++k) {
        const float4 a4 = *(const float4*)&As[k * AS_LD + ty * 4];
        const float4 bl = *(const float4*)&Bs[k * BS_LD + tx * 4];
        const float4 bh = *(const float4*)&Bs[k * BS_LD + 64 + tx * 4];
        const float am[4] = {a4.x, a4.y, a4.z, a4.w};
        const float bn[8] = {bl.x, bl.y, bl.z, bl.w, bh.x, bh.y, bh.z, bh.w};
#pragma unroll
        for (int m = 0; m < 4; ++m)
#pragma unroll
          for (int n = 0; n < 8; ++n)
            acc[m][n] = fmaf(am[m], bn[n], acc[m][n]);
      }
    }

#pragma unroll
    for (int m = 0; m < 4; ++m) {
      const int i = rows[m];
      const float loi = lo_r[m];
      const float hii = loi + MINING;
#pragma unroll
      for (int n = 0; n < 8; ++n) {
        const int cOff = (n < 4) ? (tx * 4 + n) : (64 + tx * 4 + (n - 4));
        const int j = cBase + cOff;
        const float D2 = rowA_r[m] + colBs[cOff] - 2.0f * acc[m][n];
        const float D = sqrtf(fmaxf(D2, 0.0f));
        if (D > loi && D < hii && j != i) {
          uint32_t c0 = 0u;
          uint32_t c1 = ((uint32_t)i << 14) | (uint32_t)j;
          tf2x32(k1h, k1l, c0, c1);
          const uint32_t bits = c0 ^ c1;
          const uint32_t mb = bits >> 9;
          const unsigned long long pk =
              ((unsigned long long)(mb + 1u) << 32) |
              (unsigned long long)(uint32_t)(16383 - j);
          if (pk > best[m]) best[m] = pk;
        }
      }
    }
  }

  __syncthreads();
  unsigned long long* red = (unsigned long long*)As;
#pragma unroll
  for (int m = 0; m < 4; ++m) red[(ty * 4 + m) * 16 + tx] = best[m];
  __syncthreads();
  if (tid < TM) {
    unsigned long long g = red[tid * 16];
#pragma unroll
    for (int t = 1; t < 16; ++t) {
      const unsigned long long v = red[tid * 16 + t];
      if (v > g) g = v;
    }
    partials[(size_t)(rBase + tid) * NSTRIP + strip] = g;
  }
}

// ---------------- K3: combine strips + fallback randint ----------------
__global__ void k3_select(const unsigned long long* __restrict__ partials,
                          int* __restrict__ negidx) {
  const int i = blockIdx.x * 256 + threadIdx.x;
  unsigned long long g = 0ull;
#pragma unroll
  for (int s = 0; s < NSTRIP; ++s) {
    const unsigned long long v = partials[(size_t)i * NSTRIP + s];
    if (v > g) g = v;
  }
  int ng;
  if (g != 0ull) {
    ng = 16383 - (int)(g & 0xFFFFFFFFull);
  } else {
    uint32_t t0 = 0u, t1 = 1u;            // k2 = block(ctr=(0,1), root)
    tf2x32(0u, 1u, t0, t1);
    uint32_t u0 = 0u, u1 = 1u;            // k2b = block(ctr=(0,1), k2)
    tf2x32(t0, t1, u0, u1);
    uint32_t v0 = 0u, v1 = (uint32_t)i;   // lower_bits[i]
    tf2x32(u0, u1, v0, v1);
    ng = (int)((v0 ^ v1) & 16383u);
  }
  negidx[i] = ng;
}

// ---------------- K4: gather negatives + per-row loss ----------------
__global__ void k4_loss(const float* __restrict__ x, const float* __restrict__ invA,
                        const float* __restrict__ invP, const float* __restrict__ pos2,
                        const int* __restrict__ negidx, float* __restrict__ bsums) {
  const int w = threadIdx.x >> 6;
  const int l = threadIdx.x & 63;
  const int i = blockIdx.x * 4 + w;
  const float ia = invA[i];
  const int ng = negidx[i];
  const float ip = invP[ng];
  const float4 va = *(const float4*)&x[i * XSTRIDE + l * 4];
  const float4 vn = *(const float4*)&x[ng * XSTRIDE + DIMV + l * 4];
  const float dx = va.x * ia - vn.x * ip + EPSF;
  const float dy = va.y * ia - vn.y * ip + EPSF;
  const float dz = va.z * ia - vn.z * ip + EPSF;
  const float dw = va.w * ia - vn.w * ip + EPSF;
  float s = dx*dx + dy*dy + dz*dz + dw*dw;
  s = wave_sum(s);
  __shared__ float bs[4];
  if (l == 0) bs[w] = fmaxf(pos2[i] - s + MARGINF, 0.0f);
  __syncthreads();
  if (threadIdx.x == 0) bsums[blockIdx.x] = bs[0] + bs[1] + bs[2] + bs[3];
}

// ---------------- K5: final reduce ----------------
__global__ void k5_reduce(const float* __restrict__ bsums, float* __restrict__ out) {
  float s = 0.0f;
  for (int idx = threadIdx.x; idx < (B_N / 4); idx += 256) s += bsums[idx];
  s = wave_sum(s);
  __shared__ float acc4[4];
  if ((threadIdx.x & 63) == 0) acc4[threadIdx.x >> 6] = s;
  __syncthreads();
  if (threadIdx.x == 0)
    out[0] = (acc4[0] + acc4[1] + acc4[2] + acc4[3]) * (1.0f / (float)B_N);
}

extern "C" void kernel_launch(void* const* d_in, const int* in_sizes, int n_in,
                              void* d_out, int out_size, void* d_ws, size_t ws_size,
                              hipStream_t stream) {
  const float* x = (const float*)d_in[0];
  char* ws = (char*)d_ws;
  size_t off = 0;
  unsigned long long* partials = (unsigned long long*)(ws + off);
  off += (size_t)B_N * NSTRIP * sizeof(unsigned long long);   // 1 MiB
  float* invA = (float*)(ws + off); off += (size_t)B_N * 4;
  float* invP = (float*)(ws + off); off += (size_t)B_N * 4;
  float* rowA = (float*)(ws + off); off += (size_t)B_N * 4;
  float* colB = (float*)(ws + off); off += (size_t)B_N * 4;
  float* lo   = (float*)(ws + off); off += (size_t)B_N * 4;
  float* pos2 = (float*)(ws + off); off += (size_t)B_N * 4;
  int* negidx = (int*)(ws + off);   off += (size_t)B_N * 4;
  float* bsums = (float*)(ws + off); off += (size_t)(B_N / 4) * 4;
  unsigned short* Abf = (unsigned short*)(ws + off);
  off += (size_t)B_N * 512 * sizeof(unsigned short);          // 16 MiB
  unsigned short* Pbf = (unsigned short*)(ws + off);
  off += (size_t)B_N * 512 * sizeof(unsigned short);          // 16 MiB
  const size_t ws_need = off;
  float* out = (float*)d_out;

  hipLaunchKernelGGL(k1_stats, dim3(B_N), dim3(64), 0, stream,
                     x, invA, invP, rowA, colB, lo, pos2);
  if (ws_size >= ws_need) {
    hipLaunchKernelGGL(k1b_cvt, dim3(B_N / 4), dim3(256), 0, stream,
                       x, invA, invP, Abf, Pbf);
    hipLaunchKernelGGL(k2_mfma, dim3(B_N / 128, NSTRIP), dim3(256), 0, stream,
                       Abf, Pbf, rowA, colB, lo, partials);
  } else {
    hipLaunchKernelGGL(k2_mine, dim3(B_N / TM, NSTRIP), dim3(256), 0, stream,
                       x, invA, invP, rowA, colB, lo, partials);
  }
  hipLaunchKernelGGL(k3_select, dim3(B_N / 256), dim3(256), 0, stream,
                     partials, negidx);
  hipLaunchKernelGGL(k4_loss, dim3(B_N / 4), dim3(256), 0, stream,
                     x, invA, invP, pos2, negidx, bsums);
  hipLaunchKernelGGL(k5_reduce, dim3(1), dim3(256), 0, stream, bsums, out);
}

// Round 5
// 824.940 us; speedup vs baseline: 1.3976x; 1.2777x over previous
//
#include <hip/hip_runtime.h>
#include <stdint.h>

// Problem constants
#define B_N 16384
#define DIMV 256
#define XSTRIDE 512            // floats per sample row (2 x 256)
#define EPSF 1e-6f
#define CEF 2.56e-10f          // d * EPS^2 = 256e-12
#define TWOEPS 2e-6f
#define MINING 0.1f
#define MARGINF 0.3f
#define NSTRIP 8

typedef __attribute__((ext_vector_type(8))) short bf16x8;
typedef __attribute__((ext_vector_type(4))) float f32x4;

// ---------------- JAX threefry2x32 (exact) ----------------
__device__ __forceinline__ void tf2x32(uint32_t k0, uint32_t k1,
                                       uint32_t& x0, uint32_t& x1) {
  uint32_t k2 = k0 ^ k1 ^ 0x1BD11BDAu;
  x0 += k0; x1 += k1;
#define TFR(r) { x0 += x1; x1 = (x1 << (r)) | (x1 >> (32 - (r))); x1 ^= x0; }
  TFR(13) TFR(15) TFR(26) TFR(6)
  x0 += k1; x1 += k2 + 1u;
  TFR(17) TFR(29) TFR(16) TFR(24)
  x0 += k2; x1 += k0 + 2u;
  TFR(13) TFR(15) TFR(26) TFR(6)
  x0 += k0; x1 += k1 + 3u;
  TFR(17) TFR(29) TFR(16) TFR(24)
  x0 += k1; x1 += k2 + 4u;
  TFR(13) TFR(15) TFR(26) TFR(6)
  x0 += k2; x1 += k0 + 5u;
#undef TFR
}

// rotate via single v_alignbit_b32 (alignbit(x,x,s) == rotr(x,s))
#define TF_ROT(x, r) __builtin_amdgcn_alignbit((x), (x), 32u - (r))

// Hot-path threefry: ctr=(0, c1), key=(K0,K1); returns 23-bit mantissa bits.
// Key-schedule constants are wave-uniform -> SGPRs, hoisted by LICM.
__device__ __forceinline__ uint32_t tf_mb(uint32_t K0, uint32_t K1, uint32_t c1) {
  const uint32_t K2 = K0 ^ K1 ^ 0x1BD11BDAu;
  uint32_t x0 = K0;            // c0 + k0 with c0 == 0
  uint32_t x1 = c1 + K1;
#define R4A { x0 += x1; x1 = TF_ROT(x1, 13); x1 ^= x0; \
              x0 += x1; x1 = TF_ROT(x1, 15); x1 ^= x0; \
              x0 += x1; x1 = TF_ROT(x1, 26); x1 ^= x0; \
              x0 += x1; x1 = TF_ROT(x1, 6);  x1 ^= x0; }
#define R4B { x0 += x1; x1 = TF_ROT(x1, 17); x1 ^= x0; \
              x0 += x1; x1 = TF_ROT(x1, 29); x1 ^= x0; \
              x0 += x1; x1 = TF_ROT(x1, 16); x1 ^= x0; \
              x0 += x1; x1 = TF_ROT(x1, 24); x1 ^= x0; }
  R4A; x0 += K1; x1 += K2 + 1u;
  R4B; x0 += K2; x1 += K0 + 2u;
  R4A; x0 += K0; x1 += K1 + 3u;
  R4B; x0 += K1; x1 += K2 + 4u;
  R4A; x0 += K2; x1 += K0 + 5u;
#undef R4A
#undef R4B
  return (x0 ^ x1) >> 9;
}

__device__ __forceinline__ float wave_sum(float v) {
#pragma unroll
  for (int off = 32; off > 0; off >>= 1) v += __shfl_xor(v, off, 64);
  return v;
}

// async global->LDS DMA, 16 B per lane; LDS dest = wave-uniform base + lane*16
__device__ __forceinline__ void gl_lds16(const unsigned short* g, unsigned short* s) {
  __builtin_amdgcn_global_load_lds(
      (const __attribute__((address_space(1))) void*)g,
      (__attribute__((address_space(3))) void*)s, 16, 0, 0);
}

// RNE fp32 -> bf16(hi) + bf16(v - hi), packed hi | lo<<16
__device__ __forceinline__ uint32_t split_pack(float v) {
  const uint32_t u = __float_as_uint(v);
  const uint32_t hi = (u + 0x7FFFu + ((u >> 16) & 1u)) >> 16;
  const float hf = __uint_as_float(hi << 16);
  const float lf = v - hf;
  const uint32_t ul = __float_as_uint(lf);
  const uint32_t lo = (ul + 0x7FFFu + ((ul >> 16) & 1u)) >> 16;
  return hi | (lo << 16);
}

// ---------------- K1: per-row stats (exact fp32) ----------------
__global__ void k1_stats(const float* __restrict__ x, float* __restrict__ invA,
                         float* __restrict__ invP, float* __restrict__ rowA,
                         float* __restrict__ colB, float* __restrict__ lo,
                         float* __restrict__ pos2) {
  const int i = blockIdx.x;
  const int l = threadIdx.x;  // 0..63
  const float4 va = *(const float4*)&x[i * XSTRIDE + l * 4];
  const float4 vp = *(const float4*)&x[i * XSTRIDE + DIMV + l * 4];
  float saa = va.x*va.x + va.y*va.y + va.z*va.z + va.w*va.w;
  float spp = vp.x*vp.x + vp.y*vp.y + vp.z*vp.z + vp.w*vp.w;
  saa = wave_sum(saa); spp = wave_sum(spp);
  const float ia = 1.0f / fmaxf(sqrtf(saa), 1e-12f);
  const float ip = 1.0f / fmaxf(sqrtf(spp), 1e-12f);
  const float ax = va.x*ia, ay = va.y*ia, az = va.z*ia, aw = va.w*ia;
  const float px = vp.x*ip, py = vp.y*ip, pz = vp.z*ip, pw = vp.w*ip;
  float na2 = ax*ax + ay*ay + az*az + aw*aw;
  float np2 = px*px + py*py + pz*pz + pw*pw;
  float sa  = ax + ay + az + aw;
  float sp  = px + py + pz + pw;
  float dii = ax*px + ay*py + az*pz + aw*pw;
  const float dx = ax-px+EPSF, dy = ay-py+EPSF, dz = az-pz+EPSF, dw = aw-pw+EPSF;
  float ps = dx*dx + dy*dy + dz*dz + dw*dw;
  na2 = wave_sum(na2); np2 = wave_sum(np2); sa = wave_sum(sa);
  sp  = wave_sum(sp);  dii = wave_sum(dii); ps = wave_sum(ps);
  if (l == 0) {
    const float rA = na2 + TWOEPS * sa + CEF;
    const float cB = np2 - TWOEPS * sp;
    invA[i] = ia; invP[i] = ip; rowA[i] = rA; colB[i] = cB;
    lo[i] = sqrtf(fmaxf(rA + cB - 2.0f * dii, 0.0f));
    pos2[i] = ps;
  }
}

// ---------------- K1b: fp32 -> interleaved bf16 hi/lo workspace ----------------
__global__ void k1b_cvt(const float* __restrict__ x, const float* __restrict__ invA,
                        const float* __restrict__ invP,
                        unsigned short* __restrict__ Abf,
                        unsigned short* __restrict__ Pbf) {
  const int t = blockIdx.x * 256 + threadIdx.x;
  const int row = t >> 6, l = t & 63;
  const float ia = invA[row], ip = invP[row];
  const float4 va = *(const float4*)&x[row * XSTRIDE + l * 4];
  const float4 vp = *(const float4*)&x[row * XSTRIDE + DIMV + l * 4];
  uint4 oa, op;
  oa.x = split_pack(va.x * ia); oa.y = split_pack(va.y * ia);
  oa.z = split_pack(va.z * ia); oa.w = split_pack(va.w * ia);
  op.x = split_pack(vp.x * ip); op.y = split_pack(vp.y * ip);
  op.z = split_pack(vp.z * ip); op.w = split_pack(vp.w * ip);
  *(uint4*)&Abf[(size_t)row * 512 + l * 8] = oa;
  *(uint4*)&Pbf[(size_t)row * 512 + l * 8] = op;
}

// ---------------- K2 (fast): MFMA distance GEMM + mask + threefry argmax ------
// grid (128 row-tiles, 8 strips), block 256 (4 waves, 2x2 of 64x64 wave tiles).
// launch_bounds(256,2): the ~150-reg live state needs the 256-VGPR budget.
// (256,3) and (256,4) both capped the allocator below it -> 230-820 MB of
// scratch spill (R3/R4). (256,2) measured clean: VGPR 116, WRITE 2.2 MB.
__global__ __launch_bounds__(256, 2) void k2_mfma(
    const unsigned short* __restrict__ Abf, const unsigned short* __restrict__ Pbf,
    const float* __restrict__ rowA, const float* __restrict__ colB,
    const float* __restrict__ lo, unsigned long long* __restrict__ partials) {
  __shared__ __align__(16) unsigned short As[128 * 64];
  __shared__ __align__(16) unsigned short Bs[128 * 64];
  __shared__ unsigned long long red[128][2];

  const int tid = threadIdx.x;
  const int w = tid >> 6;
  const int l = tid & 63;
  const int q = l >> 4;
  const int c16 = l & 15;
  const int rBase = blockIdx.x * 128;
  const int strip = blockIdx.y;
  const int wR = (w >> 1) * 64;
  const int wC = (w & 1) * 64;

  // threefry subkey k1 = block(ctr=(0,0), key=(0,1)) -- wave-uniform (SGPR)
  uint32_t K0 = 0u, K1 = 0u;
  tf2x32(0u, 1u, K0, K1);

  const int sw = c16 & 7;                    // frag-read xor (row&7 == c16&7)
  const int sgk = (l & 7) ^ ((l >> 3) & 7);  // staging lane's global k-group

  const int arow = rBase + w * 32 + (l >> 3);
  const unsigned short* gA0 = Abf + (size_t)arow * 512 + sgk * 8;
  unsigned short* lA0 = &As[(w * 32) * 64];
  unsigned short* lB0 = &Bs[(w * 32) * 64];

  // per-row mask bounds in D^2-space, with rowA folded in:
  //  mask <=> Lr < colB - 2*dot < Hr
  float Lr[16], Hr[16];
  const int iBase = rBase + wR + q * 4;
#pragma unroll
  for (int ri = 0; ri < 16; ++ri) {
    const int i = iBase + (ri >> 2) * 16 + (ri & 3);
    const float ra = rowA[i];
    const float lv = lo[i];
    Lr[ri] = lv * lv - ra;
    Hr[ri] = (lv + MINING) * (lv + MINING) - ra;
  }

  // 32-bit running argmax state. Per-thread scan order is strictly
  // increasing j, so strict-greater keeps the smallest j on mb ties --
  // exactly JAX argmax first-index semantics.
  int bmb[16], bj[16];
#pragma unroll
  for (int ri = 0; ri < 16; ++ri) { bmb[ri] = -1; bj[ri] = 0; }

  for (int ct = 0; ct < 16; ++ct) {
    const int cBase = strip * 2048 + ct * 128;
    const int brow = cBase + w * 32 + (l >> 3);
    const unsigned short* gB0 = Pbf + (size_t)brow * 512 + sgk * 8;

    f32x4 acc[4][4];
#pragma unroll
    for (int m = 0; m < 4; ++m)
#pragma unroll
      for (int n = 0; n < 4; ++n) {
        f32x4 z = {0.0f, 0.0f, 0.0f, 0.0f};
        acc[m][n] = z;
      }

    for (int kc = 0; kc < 512; kc += 64) {
      __syncthreads();
#pragma unroll
      for (int u = 0; u < 4; ++u) {
        gl_lds16(gA0 + kc + u * 8 * 512, lA0 + u * 8 * 64);
        gl_lds16(gB0 + kc + u * 8 * 512, lB0 + u * 8 * 64);
      }
      __syncthreads();
#pragma unroll
      for (int ks = 0; ks < 2; ++ks) {
        const int px = ((ks * 4 + q) ^ sw) * 8;
        bf16x8 am[4], bn[4];
#pragma unroll
        for (int m = 0; m < 4; ++m)
          am[m] = *(const bf16x8*)&As[(wR + m * 16 + c16) * 64 + px];
#pragma unroll
        for (int n = 0; n < 4; ++n)
          bn[n] = *(const bf16x8*)&Bs[(wC + n * 16 + c16) * 64 + px];
#pragma unroll
        for (int m = 0; m < 4; ++m)
#pragma unroll
          for (int n = 0; n < 4; ++n)
            acc[m][n] = __builtin_amdgcn_mfma_f32_16x16x32_bf16(
                am[m], bn[n], acc[m][n], 0, 0, 0);
      }
    }

    // epilogue: mask + threefry + running argmax (unconditional threefry --
    // ~45% mask density makes wave-granularity skipping worthless)
    int jc[4]; float colBc[4];
#pragma unroll
    for (int n = 0; n < 4; ++n) {
      jc[n] = cBase + wC + n * 16 + c16;
      colBc[n] = colB[jc[n]];
    }
#pragma unroll
    for (int ri = 0; ri < 16; ++ri) {
      const int m = ri >> 2, r = ri & 3;
      const int i = iBase + m * 16 + r;
      const uint32_t ihi = ((uint32_t)i) << 14;
      const float Lv = Lr[ri], Hv = Hr[ri];
      int b = bmb[ri], j0 = bj[ri];
#pragma unroll
      for (int n = 0; n < 4; ++n) {
        const float t = fmaf(-2.0f, acc[m][n][r], colBc[n]);
        const uint32_t mb = tf_mb(K0, K1, ihi | (uint32_t)jc[n]);
        const bool upd = (t > Lv) & (t < Hv) & (jc[n] != i) & ((int)mb > b);
        b  = upd ? (int)mb : b;
        j0 = upd ? jc[n] : j0;
      }
      bmb[ri] = b; bj[ri] = j0;
    }
  }

  // pack (mb, j) -> 64-bit key, reduce across the 16 col-lanes, then across
  // the 2 col-wave-groups
#pragma unroll
  for (int ri = 0; ri < 16; ++ri) {
    unsigned long long bk = 0ull;
    if (bmb[ri] >= 0)
      bk = ((unsigned long long)(uint32_t)(bmb[ri] + 1) << 32) |
           (unsigned long long)(uint32_t)(16383 - bj[ri]);
#pragma unroll
    for (int off = 1; off < 16; off <<= 1) {
      const unsigned long long o = __shfl_xor(bk, off, 64);
      if (o > bk) bk = o;
    }
    if (c16 == 0) red[wR + (ri >> 2) * 16 + q * 4 + (ri & 3)][w & 1] = bk;
  }
  __syncthreads();
  if (tid < 128) {
    const unsigned long long g0 = red[tid][0], g1 = red[tid][1];
    partials[(size_t)(rBase + tid) * NSTRIP + strip] = g0 > g1 ? g0 : g1;
  }
}

// ---------------- K2 (fallback, fp32 vector version) ----------------
#define TM 64
#define TN 128
#define KC 64
#define AS_LD 68
#define BS_LD 132
#define COLS_PER_STRIP (B_N / NSTRIP)
#define TILES_PER_STRIP (COLS_PER_STRIP / TN)

__global__ __launch_bounds__(256, 3) void k2_mine(
    const float* __restrict__ x, const float* __restrict__ invA,
    const float* __restrict__ invP, const float* __restrict__ rowA,
    const float* __restrict__ colB, const float* __restrict__ lo,
    unsigned long long* __restrict__ partials) {
  __shared__ __align__(16) float As[KC * AS_LD];
  __shared__ __align__(16) float Bs[KC * BS_LD];
  __shared__ float colBs[TN];

  const int tid = threadIdx.x;
  const int ty = tid >> 4;
  const int tx = tid & 15;
  const int rBase = blockIdx.x * TM;
  const int strip = blockIdx.y;
  const int cStart = strip * COLS_PER_STRIP;

  uint32_t k1h = 0u, k1l = 0u;
  tf2x32(0u, 1u, k1h, k1l);

  float rowA_r[4], lo_r[4];
  int rows[4];
#pragma unroll
  for (int m = 0; m < 4; ++m) {
    rows[m] = rBase + ty * 4 + m;
    rowA_r[m] = rowA[rows[m]];
    lo_r[m] = lo[rows[m]];
  }

  unsigned long long best[4] = {0ull, 0ull, 0ull, 0ull};
  const int skq = tid & 15;
  const int srr = tid >> 4;

  for (int ct = 0; ct < TILES_PER_STRIP; ++ct) {
    const int cBase = cStart + ct * TN;
    float acc[4][8];
#pragma unroll
    for (int m = 0; m < 4; ++m)
#pragma unroll
      for (int n = 0; n < 8; ++n) acc[m][n] = 0.0f;

    for (int kc = 0; kc < DIMV; kc += KC) {
      __syncthreads();
#pragma unroll
      for (int u = 0; u < 4; ++u) {
        const int r = srr + 16 * u;
        const int row = rBase + r;
        const float4 v = *(const float4*)&x[row * XSTRIDE + kc + skq * 4];
        const float s = invA[row];
        As[(skq * 4 + 0) * AS_LD + r] = v.x * s;
        As[(skq * 4 + 1) * AS_LD + r] = v.y * s;
        As[(skq * 4 + 2) * AS_LD + r] = v.z * s;
        As[(skq * 4 + 3) * AS_LD + r] = v.w * s;
      }
#pragma unroll
      for (int u = 0; u < 8; ++u) {
        const int c = srr + 16 * u;
        const int col = cBase + c;
        const float4 v = *(const float4*)&x[col * XSTRIDE + DIMV + kc + skq * 4];
        const float s = invP[col];
        Bs[(skq * 4 + 0) * BS_LD + c] = v.x * s;
        Bs[(skq * 4 + 1) * BS_LD + c] = v.y * s;
        Bs[(skq * 4 + 2) * BS_LD + c] = v.z * s;
        Bs[(skq * 4 + 3) * BS_LD + c] = v.w * s;
      }
      if (kc == 0 && tid < TN) colBs[tid] = colB[cBase + tid];
      __syncthreads();

#pragma unroll 8
      for (int k = 0; k < KC; ++k) {
        const float4 a4 = *(const float4*)&As[k * AS_LD + ty * 4];
        const float4 bl = *(const float4*)&Bs[k * BS_LD + tx * 4];
        const float4 bh = *(const float4*)&Bs[k * BS_LD + 64 + tx * 4];
        const float am[4] = {a4.x, a4.y, a4.z, a4.w};
        const float bn[8] = {bl.x, bl.y, bl.z, bl.w, bh.x, bh.y, bh.z, bh.w};
#pragma unroll
        for (int m = 0; m < 4; ++m)
#pragma unroll
          for (int n = 0; n < 8; ++n)
            acc[m][n] = fmaf(am[m], bn[n], acc[m][n]);
      }
    }

#pragma unroll
    for (int m = 0; m < 4; ++m) {
      const int i = rows[m];
      const float loi = lo_r[m];
      const float hii = loi + MINING;
#pragma unroll
      for (int n = 0; n < 8; ++n) {
        const int cOff = (n < 4) ? (tx * 4 + n) : (64 + tx * 4 + (n - 4));
        const int j = cBase + cOff;
        const float D2 = rowA_r[m] + colBs[cOff] - 2.0f * acc[m][n];
        const float D = sqrtf(fmaxf(D2, 0.0f));
        if (D > loi && D < hii && j != i) {
          uint32_t c0 = 0u;
          uint32_t c1 = ((uint32_t)i << 14) | (uint32_t)j;
          tf2x32(k1h, k1l, c0, c1);
          const uint32_t bits = c0 ^ c1;
          const uint32_t mb = bits >> 9;
          const unsigned long long pk =
              ((unsigned long long)(mb + 1u) << 32) |
              (unsigned long long)(uint32_t)(16383 - j);
          if (pk > best[m]) best[m] = pk;
        }
      }
    }
  }

  __syncthreads();
  unsigned long long* red = (unsigned long long*)As;
#pragma unroll
  for (int m = 0; m < 4; ++m) red[(ty * 4 + m) * 16 + tx] = best[m];
  __syncthreads();
  if (tid < TM) {
    unsigned long long g = red[tid * 16];
#pragma unroll
    for (int t = 1; t < 16; ++t) {
      const unsigned long long v = red[tid * 16 + t];
      if (v > g) g = v;
    }
    partials[(size_t)(rBase + tid) * NSTRIP + strip] = g;
  }
}

// ---------------- K3: combine strips + fallback randint ----------------
__global__ void k3_select(const unsigned long long* __restrict__ partials,
                          int* __restrict__ negidx) {
  const int i = blockIdx.x * 256 + threadIdx.x;
  unsigned long long g = 0ull;
#pragma unroll
  for (int s = 0; s < NSTRIP; ++s) {
    const unsigned long long v = partials[(size_t)i * NSTRIP + s];
    if (v > g) g = v;
  }
  int ng;
  if (g != 0ull) {
    ng = 16383 - (int)(g & 0xFFFFFFFFull);
  } else {
    uint32_t t0 = 0u, t1 = 1u;            // k2 = block(ctr=(0,1), root)
    tf2x32(0u, 1u, t0, t1);
    uint32_t u0 = 0u, u1 = 1u;            // k2b = block(ctr=(0,1), k2)
    tf2x32(t0, t1, u0, u1);
    uint32_t v0 = 0u, v1 = (uint32_t)i;   // lower_bits[i]
    tf2x32(u0, u1, v0, v1);
    ng = (int)((v0 ^ v1) & 16383u);
  }
  negidx[i] = ng;
}

// ---------------- K4: gather negatives + per-row loss ----------------
__global__ void k4_loss(const float* __restrict__ x, const float* __restrict__ invA,
                        const float* __restrict__ invP, const float* __restrict__ pos2,
                        const int* __restrict__ negidx, float* __restrict__ bsums) {
  const int w = threadIdx.x >> 6;
  const int l = threadIdx.x & 63;
  const int i = blockIdx.x * 4 + w;
  const float ia = invA[i];
  const int ng = negidx[i];
  const float ip = invP[ng];
  const float4 va = *(const float4*)&x[i * XSTRIDE + l * 4];
  const float4 vn = *(const float4*)&x[ng * XSTRIDE + DIMV + l * 4];
  const float dx = va.x * ia - vn.x * ip + EPSF;
  const float dy = va.y * ia - vn.y * ip + EPSF;
  const float dz = va.z * ia - vn.z * ip + EPSF;
  const float dw = va.w * ia - vn.w * ip + EPSF;
  float s = dx*dx + dy*dy + dz*dz + dw*dw;
  s = wave_sum(s);
  __shared__ float bs[4];
  if (l == 0) bs[w] = fmaxf(pos2[i] - s + MARGINF, 0.0f);
  __syncthreads();
  if (threadIdx.x == 0) bsums[blockIdx.x] = bs[0] + bs[1] + bs[2] + bs[3];
}

// ---------------- K5: final reduce ----------------
__global__ void k5_reduce(const float* __restrict__ bsums, float* __restrict__ out) {
  float s = 0.0f;
  for (int idx = threadIdx.x; idx < (B_N / 4); idx += 256) s += bsums[idx];
  s = wave_sum(s);
  __shared__ float acc4[4];
  if ((threadIdx.x & 63) == 0) acc4[threadIdx.x >> 6] = s;
  __syncthreads();
  if (threadIdx.x == 0)
    out[0] = (acc4[0] + acc4[1] + acc4[2] + acc4[3]) * (1.0f / (float)B_N);
}

extern "C" void kernel_launch(void* const* d_in, const int* in_sizes, int n_in,
                              void* d_out, int out_size, void* d_ws, size_t ws_size,
                              hipStream_t stream) {
  const float* x = (const float*)d_in[0];
  char* ws = (char*)d_ws;
  size_t off = 0;
  unsigned long long* partials = (unsigned long long*)(ws + off);
  off += (size_t)B_N * NSTRIP * sizeof(unsigned long long);   // 1 MiB
  float* invA = (float*)(ws + off); off += (size_t)B_N * 4;
  float* invP = (float*)(ws + off); off += (size_t)B_N * 4;
  float* rowA = (float*)(ws + off); off += (size_t)B_N * 4;
  float* colB = (float*)(ws + off); off += (size_t)B_N * 4;
  float* lo   = (float*)(ws + off); off += (size_t)B_N * 4;
  float* pos2 = (float*)(ws + off); off += (size_t)B_N * 4;
  int* negidx = (int*)(ws + off);   off += (size_t)B_N * 4;
  float* bsums = (float*)(ws + off); off += (size_t)(B_N / 4) * 4;
  unsigned short* Abf = (unsigned short*)(ws + off);
  off += (size_t)B_N * 512 * sizeof(unsigned short);          // 16 MiB
  unsigned short* Pbf = (unsigned short*)(ws + off);
  off += (size_t)B_N * 512 * sizeof(unsigned short);          // 16 MiB
  const size_t ws_need = off;
  float* out = (float*)d_out;

  hipLaunchKernelGGL(k1_stats, dim3(B_N), dim3(64), 0, stream,
                     x, invA, invP, rowA, colB, lo, pos2);
  if (ws_size >= ws_need) {
    hipLaunchKernelGGL(k1b_cvt, dim3(B_N / 4), dim3(256), 0, stream,
                       x, invA, invP, Abf, Pbf);
    hipLaunchKernelGGL(k2_mfma, dim3(B_N / 128, NSTRIP), dim3(256), 0, stream,
                       Abf, Pbf, rowA, colB, lo, partials);
  } else {
    hipLaunchKernelGGL(k2_mine, dim3(B_N / TM, NSTRIP), dim3(256), 0, stream,
                       x, invA, invP, rowA, colB, lo, partials);
  }
  hipLaunchKernelGGL(k3_select, dim3(B_N / 256), dim3(256), 0, stream,
                     partials, negidx);
  hipLaunchKernelGGL(k4_loss, dim3(B_N / 4), dim3(256), 0, stream,
                     x, invA, invP, pos2, negidx, bsums);
  hipLaunchKernelGGL(k5_reduce, dim3(1), dim3(256), 0, stream, bsums, out);
}